// Round 8
// baseline (282.365 us; speedup 1.0000x reference)
//
#include <hip/hip_runtime.h>

// DigitCaps on MI355X, fp32 I/O, R8.
// R2: fp32 atomicAdd = CAS loop -> native int atomics only (LDS).
// R3: seg sums are winner-biased (~3e5) -> int64 finals.
// R5/R6/R7: __launch_bounds__(256,4) forces 64 VGPR; the ~110-VGPR inner loop
//   spills su/xf every m-iteration -> 125-150MB scratch WRITE_SIZE, 185MB FETCH.
//   (R5's traffic was spill too, not just its global atomics.)
// R8: __launch_bounds__(256,3) -> cap 170 VGPR, 3 blocks/CU. 2-row x 2-m loop
//   (~64 live floats) halves dc LDS reads; 32 seg replicas (2 lanes each,
//   stride 97 -> 32 banks) make vote atomics ~conflict-free.
// Constant ~60us tail across all rounds = harness/graph overhead; only
// votes_kernel is optimizable.
//
// Sizes: B=128, J=4608, INPUT_D=8, D=8, M=4 -> N=18432 votes, C=10.
// Output = concat(output[128,10], digit_caps_new[10,8]).
// Math: output[b,c] = <(1/N) sum_n u[b,n], dc_new[c]> -> only s[b,:] needed.
//
// ws layout (4B units):
//   [0]                 done counter
//   [64, 110656)        part_seg int [1152][96] (col c*9+d; d==8 -> count)
//   [110656, 700480)    part_s float [1152][512] (col = local_b*8+d)
//   [700480, 701504)    s_final float [1024]
//   ll units [350752, 351136)  seg_part long long [4][96]

#define J_POS 4608
#define WSTRIDE 264         // 256+8 pad: W b128 reads <=2-way bank alias (free)
#define SEGSTRIDE 97        // 97%32=1 -> replica r occupies bank r%32
#define NREP 32
#define NVOTES 18432.0f
#define DENOM  2359296.0f   // B*N
#define SEG_SCALE 32768.0f  // 2^15
#define INV_SEG_SCALE 3.0517578125e-5f
#define OFF_PART_SEG 64
#define OFF_PART_S   110656
#define OFF_S_FINAL  700480
#define OFF_SEG_PART_LL 350752

__global__ __launch_bounds__(256, 3) void votes_kernel(
    const float* __restrict__ x,   // [B, J, 8]
    const float* __restrict__ w,   // [J, 8, 32]
    const float* __restrict__ dc,  // [10, 8]
    int* __restrict__ part_seg,
    float* __restrict__ part_s,
    int* __restrict__ done)
{
    __shared__ float w_lds[8 * WSTRIDE];
    __shared__ __align__(16) float dc_lds[80];
    __shared__ int seg_lds[NREP * SEGSTRIDE];
    __shared__ float s_lds[64 * 8];

    const int t  = threadIdx.x;
    const int jg = blockIdx.x >> 1;
    const int h  = blockIdx.x & 1;      // batch half
    const int j0 = jg * 8;

    if (blockIdx.x == 0 && t == 0) *done = 0;   // reduce launches after us (stream order)

    // ---- stage W tile: 8 j * 256 floats; thread t loads 8 floats
    {
        const int idx = t * 8;
        const int jj = idx >> 8, rem = idx & 255;
        const float4 r0 = *(const float4*)(w + (size_t)j0 * 256 + idx);
        const float4 r1 = *(const float4*)(w + (size_t)j0 * 256 + idx + 4);
        float* dst = &w_lds[jj * WSTRIDE + rem];
        dst[0] = r0.x; dst[1] = r0.y; dst[2] = r0.z; dst[3] = r0.w;
        dst[4] = r1.x; dst[5] = r1.y; dst[6] = r1.z; dst[7] = r1.w;
    }
    if (t < 80) dc_lds[t] = dc[t];
    for (int i = t; i < NREP * SEGSTRIDE; i += 256) seg_lds[i] = 0;
    __syncthreads();

    const int jj   = t & 7;        // consecutive lanes -> consecutive j (coalesced x)
    const int brow = t >> 3;       // 0..31
    const int b1 = h * 64 + brow, b2 = b1 + 32;
    int* const segp = &seg_lds[((t >> 1) & (NREP - 1)) * SEGSTRIDE]; // 2 lanes/replica

    const float* xp1 = x + ((size_t)b1 * J_POS + j0 + jj) * 8;
    const float* xp2 = x + ((size_t)b2 * J_POS + j0 + jj) * 8;
    const float4 a0 = *(const float4*)xp1, a1 = *(const float4*)(xp1 + 4);
    const float4 c0 = *(const float4*)xp2, c1 = *(const float4*)(xp2 + 4);
    const float xf1[8] = {a0.x,a0.y,a0.z,a0.w,a1.x,a1.y,a1.z,a1.w};
    const float xf2[8] = {c0.x,c0.y,c0.z,c0.w,c1.x,c1.y,c1.z,c1.w};

    float su1[8] = {0,0,0,0,0,0,0,0};
    float su2[8] = {0,0,0,0,0,0,0,0};
    const float* wbase = &w_lds[jj * WSTRIDE];

    #pragma unroll 1       // 2 m-columns x 2 rows per pass (~64 live floats @170 cap)
    for (int p = 0; p < 2; ++p) {
        float ua1[8]={0,0,0,0,0,0,0,0}, ub1[8]={0,0,0,0,0,0,0,0};  // row1: m=2p, 2p+1
        float ua2[8]={0,0,0,0,0,0,0,0}, ub2[8]={0,0,0,0,0,0,0,0};  // row2: m=2p, 2p+1
        #pragma unroll
        for (int i = 0; i < 8; ++i) {
            const float4 w0 = *(const float4*)(wbase + i * 32 + p * 16);
            const float4 w1 = *(const float4*)(wbase + i * 32 + p * 16 + 4);
            const float4 w2 = *(const float4*)(wbase + i * 32 + p * 16 + 8);
            const float4 w3 = *(const float4*)(wbase + i * 32 + p * 16 + 12);
            const float x1 = xf1[i], x2 = xf2[i];
            ua1[0]+=x1*w0.x; ua1[1]+=x1*w0.y; ua1[2]+=x1*w0.z; ua1[3]+=x1*w0.w;
            ua1[4]+=x1*w1.x; ua1[5]+=x1*w1.y; ua1[6]+=x1*w1.z; ua1[7]+=x1*w1.w;
            ub1[0]+=x1*w2.x; ub1[1]+=x1*w2.y; ub1[2]+=x1*w2.z; ub1[3]+=x1*w2.w;
            ub1[4]+=x1*w3.x; ub1[5]+=x1*w3.y; ub1[6]+=x1*w3.z; ub1[7]+=x1*w3.w;
            ua2[0]+=x2*w0.x; ua2[1]+=x2*w0.y; ua2[2]+=x2*w0.z; ua2[3]+=x2*w0.w;
            ua2[4]+=x2*w1.x; ua2[5]+=x2*w1.y; ua2[6]+=x2*w1.z; ua2[7]+=x2*w1.w;
            ub2[0]+=x2*w2.x; ub2[1]+=x2*w2.y; ub2[2]+=x2*w2.z; ub2[3]+=x2*w2.w;
            ub2[4]+=x2*w3.x; ub2[5]+=x2*w3.y; ub2[6]+=x2*w3.z; ub2[7]+=x2*w3.w;
        }

        // ---- argmax over 10 caps for 4 votes; dc reads are wave-uniform broadcast
        float bs_a1=-3.402823466e38f, bs_b1=bs_a1, bs_a2=bs_a1, bs_b2=bs_a1;
        int bc_a1=0, bc_b1=0, bc_a2=0, bc_b2=0;
        #pragma unroll
        for (int c = 0; c < 10; ++c) {
            const float4 da = *(const float4*)&dc_lds[c * 8];
            const float4 db = *(const float4*)&dc_lds[c * 8 + 4];
            const float sa1 = ua1[0]*da.x+ua1[1]*da.y+ua1[2]*da.z+ua1[3]*da.w
                            + ua1[4]*db.x+ua1[5]*db.y+ua1[6]*db.z+ua1[7]*db.w;
            const float sb1 = ub1[0]*da.x+ub1[1]*da.y+ub1[2]*da.z+ub1[3]*da.w
                            + ub1[4]*db.x+ub1[5]*db.y+ub1[6]*db.z+ub1[7]*db.w;
            const float sa2 = ua2[0]*da.x+ua2[1]*da.y+ua2[2]*da.z+ua2[3]*da.w
                            + ua2[4]*db.x+ua2[5]*db.y+ua2[6]*db.z+ua2[7]*db.w;
            const float sb2 = ub2[0]*da.x+ub2[1]*da.y+ub2[2]*da.z+ub2[3]*da.w
                            + ub2[4]*db.x+ub2[5]*db.y+ub2[6]*db.z+ub2[7]*db.w;
            if (sa1 > bs_a1) { bs_a1 = sa1; bc_a1 = c; }   // strict > = first max (jnp)
            if (sb1 > bs_b1) { bs_b1 = sb1; bc_b1 = c; }
            if (sa2 > bs_a2) { bs_a2 = sa2; bc_a2 = c; }
            if (sb2 > bs_b2) { bs_b2 = sb2; bc_b2 = c; }
        }

        // ---- native int LDS atomics, fire-and-forget
        const int oa1 = bc_a1 * 9, ob1 = bc_b1 * 9, oa2 = bc_a2 * 9, ob2 = bc_b2 * 9;
        #pragma unroll
        for (int d = 0; d < 8; ++d) {
            atomicAdd(&segp[oa1 + d], __float2int_rn(ua1[d] * SEG_SCALE));
            atomicAdd(&segp[ob1 + d], __float2int_rn(ub1[d] * SEG_SCALE));
            atomicAdd(&segp[oa2 + d], __float2int_rn(ua2[d] * SEG_SCALE));
            atomicAdd(&segp[ob2 + d], __float2int_rn(ub2[d] * SEG_SCALE));
        }
        atomicAdd(&segp[oa1 + 8], 1); atomicAdd(&segp[ob1 + 8], 1);
        atomicAdd(&segp[oa2 + 8], 1); atomicAdd(&segp[ob2 + 8], 1);

        #pragma unroll
        for (int d = 0; d < 8; ++d) {
            su1[d] += ua1[d] + ub1[d];
            su2[d] += ua2[d] + ub2[d];
        }
    }

    // ---- reduce su across the 8 jj-lanes (same wave)
    #pragma unroll
    for (int d = 0; d < 8; ++d) {
        su1[d] += __shfl_xor(su1[d], 1);
        su1[d] += __shfl_xor(su1[d], 2);
        su1[d] += __shfl_xor(su1[d], 4);
        su2[d] += __shfl_xor(su2[d], 1);
        su2[d] += __shfl_xor(su2[d], 2);
        su2[d] += __shfl_xor(su2[d], 4);
    }
    if (jj == 0) {
        #pragma unroll
        for (int d = 0; d < 8; ++d) {
            s_lds[brow * 8 + d] = su1[d];
            s_lds[(brow + 32) * 8 + d] = su2[d];
        }
    }
    __syncthreads();

    // ---- flush partials: plain coalesced stores, ZERO global atomics
    if (t < 90) {
        int v = 0;
        #pragma unroll
        for (int r = 0; r < NREP; ++r) v += seg_lds[r * SEGSTRIDE + t];
        part_seg[blockIdx.x * 96 + t] = v;
    }
    *(float2*)&part_s[(size_t)blockIdx.x * 512 + t * 2] = *(const float2*)&s_lds[t * 2];
}

// 20 blocks: 0..15 s-columns, 16..19 seg-quarters; last-done block runs the final.
__global__ __launch_bounds__(256) void reduce_final_kernel(
    const int* __restrict__ part_seg,
    const float* __restrict__ part_s,
    float* __restrict__ s_final,
    long long* __restrict__ seg_part,
    int* __restrict__ done,
    const float* __restrict__ dc,
    float* __restrict__ out)       // [0,1280): output  [1280,1360): dc_new
{
    __shared__ float red[64][5];
    __shared__ long long segred[2][96];
    __shared__ float dcn[80];
    __shared__ float sf[1024];
    __shared__ int lastflag;

    const int t = threadIdx.x;
    const int bid = blockIdx.x;

    if (bid < 16) {
        // ---- s column-reduce: 64 cols, 4 chunks of 144 rows (parity h)
        const int g0 = bid * 64;
        const int h = g0 >> 9;
        const int gl = t & 63, chunk = t >> 6;
        const int col = (g0 + gl) & 511;
        float acc = 0.f;
        #pragma unroll 8
        for (int i = chunk * 144; i < chunk * 144 + 144; ++i)
            acc += part_s[(size_t)(2 * i + h) * 512 + col];
        red[gl][chunk] = acc;
        __syncthreads();
        if (t < 64)
            __hip_atomic_store(&s_final[g0 + t],
                               red[t][0] + red[t][1] + red[t][2] + red[t][3],
                               __ATOMIC_RELAXED, __HIP_MEMORY_SCOPE_AGENT);
    } else {
        // ---- seg quarter-reduce: 288 rows, 96 cols, 2 row-chunks
        const int p = bid - 16;
        if (t < 192) {
            const int o = t % 96, rc = t / 96;
            long long acc = 0;
            const int r0 = p * 288 + rc * 144;
            #pragma unroll 8
            for (int i = r0; i < r0 + 144; ++i)
                acc += part_seg[(size_t)i * 96 + o];
            segred[rc][o] = acc;
        }
        __syncthreads();
        if (t < 96)
            __hip_atomic_store(&seg_part[p * 96 + t], segred[0][t] + segred[1][t],
                               __ATOMIC_RELAXED, __HIP_MEMORY_SCOPE_AGENT);
    }

    // ---- completion protocol: release stores, count blocks, last one finalizes
    __threadfence();
    __syncthreads();
    if (t == 0) lastflag = (atomicAdd(done, 1) == 19) ? 1 : 0;
    __syncthreads();
    if (!lastflag) return;
    __threadfence();

    // ---- final (one block): dc_new + output GEMV; agent-scope loads of partials
    #pragma unroll
    for (int r = 0; r < 4; ++r) {
        const int i = r * 256 + t;
        const float v = __hip_atomic_load(&s_final[i], __ATOMIC_RELAXED,
                                          __HIP_MEMORY_SCOPE_AGENT);
        sf[i] = v * (1.0f / NVOTES);
    }
    if (t < 80) {
        const int c = t >> 3, d = t & 7;
        long long sv = 0, cv = 0;
        #pragma unroll
        for (int p = 0; p < 4; ++p) {
            sv += __hip_atomic_load(&seg_part[p * 96 + c * 9 + d], __ATOMIC_RELAXED,
                                    __HIP_MEMORY_SCOPE_AGENT);
            cv += __hip_atomic_load(&seg_part[p * 96 + c * 9 + 8], __ATOMIC_RELAXED,
                                    __HIP_MEMORY_SCOPE_AGENT);
        }
        const float d0 = dc[t];
        const float nd = d0 + ((float)sv * INV_SEG_SCALE - (float)cv * d0) * (1.0f / DENOM);
        dcn[t] = nd;
        out[1280 + t] = nd;
    }
    __syncthreads();

    #pragma unroll
    for (int r = 0; r < 5; ++r) {
        const int idx = r * 256 + t;        // 0..1279
        const int b = idx / 10, c = idx - b * 10;
        float acc = 0.f;
        #pragma unroll
        for (int d = 0; d < 8; ++d) acc += sf[b * 8 + d] * dcn[c * 8 + d];
        out[idx] = acc;
    }
}

extern "C" void kernel_launch(void* const* d_in, const int* in_sizes, int n_in,
                              void* d_out, int out_size, void* d_ws, size_t ws_size,
                              hipStream_t stream) {
    const float* x  = (const float*)d_in[0];
    const float* w  = (const float*)d_in[1];
    const float* dc = (const float*)d_in[2];
    float* out = (float*)d_out;
    int*       done      = (int*)d_ws;
    int*       part_seg  = (int*)d_ws + OFF_PART_SEG;
    float*     part_s    = (float*)d_ws + OFF_PART_S;
    float*     s_final   = (float*)d_ws + OFF_S_FINAL;
    long long* seg_part  = (long long*)d_ws + OFF_SEG_PART_LL;

    votes_kernel<<<1152, 256, 0, stream>>>(x, w, dc, part_seg, part_s, done);
    reduce_final_kernel<<<20, 256, 0, stream>>>(part_seg, part_s, s_final,
                                                seg_part, done, dc, out);
}

// Round 9
// 99.376 us; speedup vs baseline: 2.8414x; 2.8414x over previous
//
#include <hip/hip_runtime.h>

// DigitCaps on MI355X, fp32 I/O, R9.
// R2: fp32 atomicAdd = CAS loop -> native int atomics only (LDS).
// R3: seg sums are winner-biased -> int64/exact finals.
// R5/R7/R8: ANY __launch_bounds__ VGPR cap makes the allocator spill massively
//   ((256,4)->64regs/125MB, (256,3)->84regs/407MB scratch WRITE). Only the
//   uncapped 220-reg R4 config never spilled. So: no cap, and DESIGN for
//   register residency at 2 waves/SIMD.
// R9: thread owns one (j,m) pair -> W-slice 8x8=64 floats + dc 80 floats all
//   in registers (global->reg once); per iter ONE vote entirely from regs;
//   seg AND s accumulate via replicated fixed-point LDS int atomics (no
//   shuffles); x prefetched 1-ahead. LDS read traffic ~0; plain-store flush.
// Constant ~60us tail across all rounds = harness overhead; votes_kernel is
// the entire optimizable budget.
//
// Sizes: B=128, J=4608, INPUT_D=8, D=8, M=4 -> N=18432 votes, C=10.
// Output = concat(output[128,10], digit_caps_new[10,8]).
// Math: output[b,c] = <(1/N) sum_n u[b,n], dc_new[c]> -> only s[b,:] needed.
//
// ws layout (4B units):
//   [0]                 done counter
//   [64, 110656)        part_seg int [1152][96] (col c*9+d; d==8 -> count)
//   [110656, 700480)    part_s int [1152][512] (col = local_b*8+d, scale 2^15)
//   [700480, 701504)    s_final float [1024]
//   ll units [350752, 351136)  seg_part long long [4][96]

#define J_POS 4608
#define SEGSTRIDE 97        // 97%32=1 -> replica r occupies bank r%32
#define NSEG 32
#define SSTRIDE 520         // 520%32=8 -> s replicas spread banks
#define NSREP 8
#define NVOTES 18432.0f
#define DENOM  2359296.0f   // B*N
#define SEG_SCALE 32768.0f  // 2^15
#define INV_SEG_SCALE 3.0517578125e-5f
#define OFF_PART_SEG 64
#define OFF_PART_S   110656
#define OFF_S_FINAL  700480
#define OFF_SEG_PART_LL 350752

__global__ __launch_bounds__(256) void votes_kernel(
    const float* __restrict__ x,   // [B, J, 8]
    const float* __restrict__ w,   // [J, 8, 32]
    const float* __restrict__ dc,  // [10, 8]
    int* __restrict__ part_seg,
    int* __restrict__ part_s,
    int* __restrict__ done)
{
    __shared__ int seg_lds[NSEG * SEGSTRIDE];   // 12.4 KB
    __shared__ int s_lds[NSREP * SSTRIDE];      // 16.6 KB

    const int t  = threadIdx.x;
    const int jg = blockIdx.x >> 1;
    const int h  = blockIdx.x & 1;      // batch half
    const int j0 = jg * 8;

    if (blockIdx.x == 0 && t == 0) *done = 0;   // reduce launches after us (stream order)

    for (int i = t; i < NSEG * SEGSTRIDE; i += 256) seg_lds[i] = 0;
    for (int i = t; i < NSREP * SSTRIDE; i += 256) s_lds[i] = 0;

    const int jj   = t >> 5;           // 0..7 : this thread's j
    const int m    = (t >> 3) & 3;     // 0..3 : this thread's vote column
    const int brow = t & 7;            // 0..7 : batch row within iter
    const int j = j0 + jj;

    // ---- W slice (8 i x 8 d for this (j,m)) -> 64 registers, loaded once
    float4 wra[8], wrb[8];
    {
        const float* wp = w + (size_t)j * 256 + m * 8;
        #pragma unroll
        for (int i = 0; i < 8; ++i) {
            wra[i] = *(const float4*)(wp + i * 32);
            wrb[i] = *(const float4*)(wp + i * 32 + 4);
        }
    }
    // ---- all of dc -> 80 registers (global broadcast reads, L2-served)
    float4 dca[10], dcb[10];
    #pragma unroll
    for (int c = 0; c < 10; ++c) {
        dca[c] = *(const float4*)(dc + c * 8);
        dcb[c] = *(const float4*)(dc + c * 8 + 4);
    }

    int* const segp = &seg_lds[((t >> 1) & (NSEG - 1)) * SEGSTRIDE];
    // lanes sharing one b in a wave = {jj&1, m} -> 8 distinct replicas: 1-way
    int* const sp = &s_lds[((t >> 3) & (NSREP - 1)) * SSTRIDE];

    __syncthreads();

    // ---- software-pipelined x loads (1-ahead) to hide HBM latency
    const float* xp0 = x + ((size_t)(h * 64 + brow) * J_POS + j) * 8;
    float4 nx0 = *(const float4*)xp0;
    float4 nx1 = *(const float4*)(xp0 + 4);

    #pragma unroll 1
    for (int it = 0; it < 8; ++it) {
        const int bl = it * 8 + brow;       // local b 0..63
        const float4 x0 = nx0, x1 = nx1;
        if (it < 7) {
            const float* xp = x + ((size_t)(h * 64 + bl + 8) * J_POS + j) * 8;
            nx0 = *(const float4*)xp;
            nx1 = *(const float4*)(xp + 4);
        }
        const float xf[8] = {x0.x,x0.y,x0.z,x0.w,x1.x,x1.y,x1.z,x1.w};

        // ---- one vote: u[8], all operands in registers
        float u[8] = {0,0,0,0,0,0,0,0};
        #pragma unroll
        for (int i = 0; i < 8; ++i) {
            const float xi = xf[i];
            u[0] += xi * wra[i].x; u[1] += xi * wra[i].y;
            u[2] += xi * wra[i].z; u[3] += xi * wra[i].w;
            u[4] += xi * wrb[i].x; u[5] += xi * wrb[i].y;
            u[6] += xi * wrb[i].z; u[7] += xi * wrb[i].w;
        }

        // ---- argmax over 10 caps, dc in registers (strict > = first max, jnp)
        float best = -3.402823466e38f;
        int bc = 0;
        #pragma unroll
        for (int c = 0; c < 10; ++c) {
            const float sim = u[0]*dca[c].x + u[1]*dca[c].y + u[2]*dca[c].z + u[3]*dca[c].w
                            + u[4]*dcb[c].x + u[5]*dcb[c].y + u[6]*dcb[c].z + u[7]*dcb[c].w;
            if (sim > best) { best = sim; bc = c; }
        }

        // ---- fixed-point LDS atomics, fire-and-forget
        const int o = bc * 9;
        const int sb = bl * 8;
        #pragma unroll
        for (int d = 0; d < 8; ++d) {
            const int q = __float2int_rn(u[d] * SEG_SCALE);
            atomicAdd(&segp[o + d], q);
            atomicAdd(&sp[sb + d], q);
        }
        atomicAdd(&segp[o + 8], 1);
    }

    __syncthreads();

    // ---- flush partials: plain coalesced stores, zero global atomics
    if (t < 90) {
        int v = 0;
        #pragma unroll
        for (int r = 0; r < NSEG; ++r) v += seg_lds[r * SEGSTRIDE + t];
        part_seg[blockIdx.x * 96 + t] = v;
    }
    #pragma unroll
    for (int e = t; e < 512; e += 256) {
        int v = 0;
        #pragma unroll
        for (int r = 0; r < NSREP; ++r) v += s_lds[r * SSTRIDE + e];
        part_s[(size_t)blockIdx.x * 512 + e] = v;
    }
}

// 20 blocks: 0..15 s-columns, 16..19 seg-quarters; last-done block runs the final.
__global__ __launch_bounds__(256) void reduce_final_kernel(
    const int* __restrict__ part_seg,
    const int* __restrict__ part_s,
    float* __restrict__ s_final,
    long long* __restrict__ seg_part,
    int* __restrict__ done,
    const float* __restrict__ dc,
    float* __restrict__ out)       // [0,1280): output  [1280,1360): dc_new
{
    __shared__ long long red[64][5];
    __shared__ long long segred[2][96];
    __shared__ float dcn[80];
    __shared__ float sf[1024];
    __shared__ int lastflag;

    const int t = threadIdx.x;
    const int bid = blockIdx.x;

    if (bid < 16) {
        // ---- s column-reduce: 64 cols, 4 chunks of 144 rows (parity h)
        const int g0 = bid * 64;
        const int h = g0 >> 9;
        const int gl = t & 63, chunk = t >> 6;
        const int col = (g0 + gl) & 511;
        long long acc = 0;
        #pragma unroll 8
        for (int i = chunk * 144; i < chunk * 144 + 144; ++i)
            acc += part_s[(size_t)(2 * i + h) * 512 + col];
        red[gl][chunk] = acc;
        __syncthreads();
        if (t < 64) {
            const long long v = red[t][0] + red[t][1] + red[t][2] + red[t][3];
            __hip_atomic_store(&s_final[g0 + t], (float)v * INV_SEG_SCALE,
                               __ATOMIC_RELAXED, __HIP_MEMORY_SCOPE_AGENT);
        }
    } else {
        // ---- seg quarter-reduce: 288 rows, 96 cols, 2 row-chunks
        const int p = bid - 16;
        if (t < 192) {
            const int o = t % 96, rc = t / 96;
            long long acc = 0;
            const int r0 = p * 288 + rc * 144;
            #pragma unroll 8
            for (int i = r0; i < r0 + 144; ++i)
                acc += part_seg[(size_t)i * 96 + o];
            segred[rc][o] = acc;
        }
        __syncthreads();
        if (t < 96)
            __hip_atomic_store(&seg_part[p * 96 + t], segred[0][t] + segred[1][t],
                               __ATOMIC_RELAXED, __HIP_MEMORY_SCOPE_AGENT);
    }

    // ---- completion protocol: release stores, count blocks, last one finalizes
    __threadfence();
    __syncthreads();
    if (t == 0) lastflag = (atomicAdd(done, 1) == 19) ? 1 : 0;
    __syncthreads();
    if (!lastflag) return;
    __threadfence();

    // ---- final (one block): dc_new + output GEMV; agent-scope loads of partials
    #pragma unroll
    for (int r = 0; r < 4; ++r) {
        const int i = r * 256 + t;
        const float v = __hip_atomic_load(&s_final[i], __ATOMIC_RELAXED,
                                          __HIP_MEMORY_SCOPE_AGENT);
        sf[i] = v * (1.0f / NVOTES);
    }
    if (t < 80) {
        const int c = t >> 3, d = t & 7;
        long long sv = 0, cv = 0;
        #pragma unroll
        for (int p = 0; p < 4; ++p) {
            sv += __hip_atomic_load(&seg_part[p * 96 + c * 9 + d], __ATOMIC_RELAXED,
                                    __HIP_MEMORY_SCOPE_AGENT);
            cv += __hip_atomic_load(&seg_part[p * 96 + c * 9 + 8], __ATOMIC_RELAXED,
                                    __HIP_MEMORY_SCOPE_AGENT);
        }
        const float d0 = dc[t];
        const float nd = d0 + ((float)sv * INV_SEG_SCALE - (float)cv * d0) * (1.0f / DENOM);
        dcn[t] = nd;
        out[1280 + t] = nd;
    }
    __syncthreads();

    #pragma unroll
    for (int r = 0; r < 5; ++r) {
        const int idx = r * 256 + t;        // 0..1279
        const int b = idx / 10, c = idx - b * 10;
        float acc = 0.f;
        #pragma unroll
        for (int d = 0; d < 8; ++d) acc += sf[b * 8 + d] * dcn[c * 8 + d];
        out[idx] = acc;
    }
}

extern "C" void kernel_launch(void* const* d_in, const int* in_sizes, int n_in,
                              void* d_out, int out_size, void* d_ws, size_t ws_size,
                              hipStream_t stream) {
    const float* x  = (const float*)d_in[0];
    const float* w  = (const float*)d_in[1];
    const float* dc = (const float*)d_in[2];
    float* out = (float*)d_out;
    int*       done      = (int*)d_ws;
    int*       part_seg  = (int*)d_ws + OFF_PART_SEG;
    int*       part_s    = (int*)d_ws + OFF_PART_S;
    float*     s_final   = (float*)d_ws + OFF_S_FINAL;
    long long* seg_part  = (long long*)d_ws + OFF_SEG_PART_LL;

    votes_kernel<<<1152, 256, 0, stream>>>(x, w, dc, part_seg, part_s, done);
    reduce_final_kernel<<<20, 256, 0, stream>>>(part_seg, part_s, s_final,
                                                seg_part, done, dc, out);
}